// Round 4
// baseline (262.055 us; speedup 1.0000x reference)
//
#include <hip/hip_runtime.h>
#include <math.h>

#define ZB 2
#define NN 4096
#define KNNv 30
#define EDIM 256
#define DM 128
#define HBINS 2048
#define CAPW 256

typedef __attribute__((ext_vector_type(8))) short bf16x8;
typedef __attribute__((ext_vector_type(4))) float fx4;

#define ELN_STR 264   // bf16 elems; 528B rows, 16B-aligned

static __device__ inline unsigned short f2bf(float f) {
    unsigned int u = __float_as_uint(f);
    unsigned int r = u + 0x7fffu + ((u >> 16) & 1u);   // RNE
    return (unsigned short)(r >> 16);
}

// ---- prep: dense Ca as float4 ------------------------------------------
__global__ __launch_bounds__(256) void caprep_kernel(
    const float* __restrict__ C, float4* __restrict__ Ca4)
{
    int tid = blockIdx.x * 256 + threadIdx.x;
    if (tid < ZB * NN) {
        const float* p = C + (size_t)tid * 12 + 3;
        Ca4[tid] = make_float4(p[0], p[1], p[2], 0.0f);
    }
}

// ---- prep: Wt[n][k] = bf16(W[k][n] * gamma[k]) -------------------------
__global__ __launch_bounds__(256) void wprep_kernel(
    const float* __restrict__ W, const float* __restrict__ gamma_,
    unsigned short* __restrict__ Wt)
{
    int base = blockIdx.x * 1024 + threadIdx.x;
    #pragma unroll
    for (int q = 0; q < 4; ++q) {
        int idx = base + q * 256;
        int k = idx >> 7, n = idx & 127;
        Wt[n * 256 + k] = f2bf(W[idx] * gamma_[k]);
    }
}

// ---- prep: bias2[n] = b[n] + beta @ W ----------------------------------
__global__ __launch_bounds__(128) void biasprep_kernel(
    const float* __restrict__ W, const float* __restrict__ beta_,
    const float* __restrict__ bias, float* __restrict__ bias2)
{
    int n = threadIdx.x;
    float acc = bias[n];
    #pragma unroll 8
    for (int k = 0; k < EDIM; ++k) acc += beta_[k] * W[k * 128 + n];
    bias2[n] = acc;
}

// ---- KNN: one wave per 2 nodes; wave-private packed histogram ----------
static __device__ inline void keys2(float4 p, float4 c0, float4 c1,
                                    bool m0, bool m1,
                                    unsigned int& k0, unsigned int& k1)
{
    float dx0 = p.x - c0.x, dy0 = p.y - c0.y, dz0 = p.z - c0.z;
    float s0 = dx0 * dx0 + dy0 * dy0 + dz0 * dz0;
    if (s0 == 0.0f || m0) s0 = __builtin_inff();
    k0 = __float_as_uint(s0);
    float dx1 = p.x - c1.x, dy1 = p.y - c1.y, dz1 = p.z - c1.z;
    float s1 = dx1 * dx1 + dy1 * dy1 + dz1 * dz1;
    if (s1 == 0.0f || m1) s1 = __builtin_inff();
    k1 = __float_as_uint(s1);
}

__global__ __launch_bounds__(256) void knn_kernel(
    const float4* __restrict__ Ca4,
    const unsigned char* __restrict__ node_mask,
    float* __restrict__ out_kidx,
    float* __restrict__ out_emask)
{
    __shared__ unsigned int hist[4][HBINS];          // u16x2-packed per wave
    __shared__ unsigned long long buf[4][2][CAPW];
    __shared__ unsigned int mcnt[4][2];

    const int t = threadIdx.x;
    const int wv = t >> 6, lane = t & 63;
    const int node0 = (blockIdx.x * 4 + wv) * 2;     // even: pair never crosses batch
    const int z = node0 >> 12;

    {   // zero this wave's hist (uint4) + counters
        uint4* hz = (uint4*)&hist[wv][lane * 32];
        #pragma unroll
        for (int q = 0; q < 8; ++q) hz[q] = make_uint4(0u, 0u, 0u, 0u);
        if (lane < 2) mcnt[wv][lane] = 0u;
    }

    const float4 c0 = Ca4[node0];
    const float4 c1 = Ca4[node0 + 1];
    const bool m0 = node_mask[node0] != 0;
    const bool m1 = node_mask[node0 + 1] != 0;
    const float4* Cz = Ca4 + ((size_t)z << 12);
    __syncthreads();

    // pass 1: packed histogram (node0 in low16, node1 in high16)
    #pragma unroll 4
    for (int q = 0; q < 64; ++q) {
        float4 p = Cz[q * 64 + lane];
        unsigned int k0, k1;
        keys2(p, c0, c1, m0, m1, k0, k1);
        atomicAdd(&hist[wv][k0 >> 21], 1u);
        atomicAdd(&hist[wv][k1 >> 21], 0x10000u);
    }
    __syncthreads();

    // scan: lane owns bins [lane*32, lane*32+32)
    uint4 ch[8];
    unsigned int lsum = 0;
    {
        const uint4* hp = (const uint4*)&hist[wv][lane * 32];
        #pragma unroll
        for (int q = 0; q < 8; ++q) {
            ch[q] = hp[q];
            lsum += ch[q].x + ch[q].y + ch[q].z + ch[q].w;   // packed-safe (<=4096/half)
        }
    }
    unsigned int incl = lsum;
    #pragma unroll
    for (int off = 1; off < 64; off <<= 1) {
        unsigned int v = __shfl_up(incl, off);
        if (lane >= off) incl += v;
    }
    const unsigned int excl = incl - lsum;

    int cutl = -1, cuth = -1;
    {
        unsigned int run_lo = excl & 0xffffu, run_hi = excl >> 16;
        #pragma unroll
        for (int q = 0; q < 32; ++q) {
            unsigned int pk = ((const unsigned int*)ch)[q];
            unsigned int clo = pk & 0xffffu, chi = pk >> 16;
            if (run_lo < KNNv && run_lo + clo >= KNNv) cutl = lane * 32 + q;
            if (run_hi < KNNv && run_hi + chi >= KNNv) cuth = lane * 32 + q;
            run_lo += clo; run_hi += chi;
        }
    }
    unsigned long long b0 = __ballot(cutl >= 0);
    unsigned long long b1 = __ballot(cuth >= 0);
    const int cut0 = __shfl(cutl, (int)__builtin_ctzll(b0));
    const int cut1 = __shfl(cuth, (int)__builtin_ctzll(b1));

    // pass 2: collect candidates (recompute keys identically)
    #pragma unroll 2
    for (int q = 0; q < 64; ++q) {
        const int j = q * 64 + lane;
        float4 p = Cz[j];
        unsigned int k0, k1;
        keys2(p, c0, c1, m0, m1, k0, k1);
        if ((int)(k0 >> 21) <= cut0) {
            unsigned int pos = atomicAdd(&mcnt[wv][0], 1u);
            if (pos < CAPW) buf[wv][0][pos] = ((unsigned long long)k0 << 32) | (unsigned int)j;
        }
        if ((int)(k1 >> 21) <= cut1) {
            unsigned int pos = atomicAdd(&mcnt[wv][1], 1u);
            if (pos < CAPW) buf[wv][1][pos] = ((unsigned long long)k1 << 32) | (unsigned int)j;
        }
    }
    __syncthreads();

    // rank candidates; write winners straight to global
    #pragma unroll
    for (int h = 0; h < 2; ++h) {
        const int bi = node0 + h;
        const bool mi = h ? m1 : m0;
        unsigned int M = mcnt[wv][h]; if (M > CAPW) M = CAPW;
        for (unsigned int c = lane; c < M; c += 64) {
            unsigned long long me = buf[wv][h][c];
            unsigned int r = 0;
            for (unsigned int o = 0; o < M; ++o) r += (buf[wv][h][o] < me) ? 1u : 0u;
            if (r < KNNv) {
                unsigned int k = (unsigned int)(me >> 32);
                int j = (int)(me & 0xffffffffu);
                float sv = __uint_as_float(k);
                bool nb = node_mask[((size_t)z << 12) + j] != 0;
                bool em = (!mi && !nb) && (sv != 0.0f) && (sv < 144.0f);
                int kv = em ? j : (bi & (NN - 1));
                size_t o = (size_t)bi * KNNv + r;
                out_kidx[o]  = (float)kv;
                out_emask[o] = em ? 1.0f : 0.0f;
            }
        }
    }
}

// ---- Edges: RBF+LN (bf16) -> MFMA GEMM ---------------------------------
__global__ __launch_bounds__(256) void edge_kernel(
    const float* __restrict__ C,
    const float* __restrict__ kidxf,
    const float* __restrict__ centers,
    const unsigned short* __restrict__ Wt,
    const float* __restrict__ bias2,
    float* __restrict__ outE)
{
    __shared__ unsigned short Eln[64 * ELN_STR];
    const int t = threadIdx.x;
    const long g0 = (long)blockIdx.x * 64;

    {   // phase 1: 4 threads/edge
        const int e   = t >> 2;
        const int sub = t & 3;
        const long g = g0 + e;
        const int z   = (int)(g / (NN * KNNv));
        const int rem = (int)(g - (long)z * NN * KNNv);
        const int i   = rem / KNNv;
        const int j   = (int)kidxf[g];

        const float* Ci = C + (((size_t)z * NN + i) * 4 + sub) * 3;
        const float ax = Ci[0], ay = Ci[1], az = Ci[2];
        const float4* Cj4 = (const float4*)(C + ((size_t)z * NN + j) * 12);
        float4 q0 = Cj4[0], q1 = Cj4[1], q2 = Cj4[2];
        const float bx[4] = {q0.x, q0.w, q1.z, q2.y};
        const float by[4] = {q0.y, q1.x, q1.w, q2.z};
        const float bz[4] = {q0.z, q1.y, q2.x, q2.w};

        float d[4];
        #pragma unroll
        for (int b = 0; b < 4; ++b) {
            float dx = ax - bx[b], dy = ay - by[b], dz = az - bz[b];
            float s = dx * dx + dy * dy + dz * dz;
            d[b] = s > 0.0f ? sqrtf(s) : 0.0f;
        }
        float cen[16];
        #pragma unroll
        for (int r = 0; r < 16; ++r) cen[r] = centers[r];

        float vals[64];
        float sum = 0.f, sumsq = 0.f;
        #pragma unroll
        for (int b = 0; b < 4; ++b) {
            #pragma unroll
            for (int r = 0; r < 16; ++r) {
                float dd = d[b] - cen[r];
                float v = __expf(dd * dd * -0.64f);
                vals[b * 16 + r] = v;
                sum += v; sumsq += v * v;
            }
        }
        sum   += __shfl_xor(sum, 1);   sum   += __shfl_xor(sum, 2);
        sumsq += __shfl_xor(sumsq, 1); sumsq += __shfl_xor(sumsq, 2);
        const float mu   = sum * (1.0f / 256.0f);
        const float var  = sumsq * (1.0f / 256.0f) - mu * mu;
        const float rstd = rsqrtf(var + 1e-5f);
        #pragma unroll
        for (int w = 0; w < 8; ++w) {
            bf16x8 pk;
            #pragma unroll
            for (int v = 0; v < 8; ++v)
                pk[v] = (short)f2bf((vals[w * 8 + v] - mu) * rstd);
            *(bf16x8*)&Eln[e * ELN_STR + sub * 64 + w * 8] = pk;
        }
    }
    __syncthreads();

    {   // phase 2: MFMA, wave -> 32 cols
        const int lane = t & 63;
        const int wv   = t >> 6;
        const int quad = lane >> 4;
        const int l15  = lane & 15;
        const int n0   = wv * 32;

        bf16x8 Bf[2][8];
        #pragma unroll
        for (int nt = 0; nt < 2; ++nt)
            #pragma unroll
            for (int ks = 0; ks < 8; ++ks)
                Bf[nt][ks] = *(const bf16x8*)(Wt + (size_t)(n0 + nt * 16 + l15) * 256
                                                 + ks * 32 + quad * 8);

        fx4 acc[4][2];
        #pragma unroll
        for (int mt = 0; mt < 4; ++mt)
            #pragma unroll
            for (int nt = 0; nt < 2; ++nt)
                acc[mt][nt] = (fx4){0.f, 0.f, 0.f, 0.f};

        #pragma unroll
        for (int ks = 0; ks < 8; ++ks) {
            bf16x8 Af[4];
            #pragma unroll
            for (int mt = 0; mt < 4; ++mt)
                Af[mt] = *(const bf16x8*)&Eln[(mt * 16 + l15) * ELN_STR + ks * 32 + quad * 8];
            #pragma unroll
            for (int mt = 0; mt < 4; ++mt) {
                acc[mt][0] = __builtin_amdgcn_mfma_f32_16x16x32_bf16(Af[mt], Bf[0][ks], acc[mt][0], 0, 0, 0);
                acc[mt][1] = __builtin_amdgcn_mfma_f32_16x16x32_bf16(Af[mt], Bf[1][ks], acc[mt][1], 0, 0, 0);
            }
        }

        const float bb0 = bias2[n0 + l15];
        const float bb1 = bias2[n0 + 16 + l15];
        #pragma unroll
        for (int mt = 0; mt < 4; ++mt) {
            #pragma unroll
            for (int r = 0; r < 4; ++r) {
                const long row = g0 + mt * 16 + quad * 4 + r;
                float* orow = outE + (size_t)row * DM;
                orow[n0 + l15]      = acc[mt][0][r] + bb0;
                orow[n0 + 16 + l15] = acc[mt][1][r] + bb1;
            }
        }
    }
}

extern "C" void kernel_launch(void* const* d_in, const int* in_sizes, int n_in,
                              void* d_out, int out_size, void* d_ws, size_t ws_size,
                              hipStream_t stream) {
    const float* C          = (const float*)d_in[0];
    const unsigned char* nm = (const unsigned char*)d_in[1];
    const float* centers    = (const float*)d_in[2];
    const float* gamma_     = (const float*)d_in[3];
    const float* beta_      = (const float*)d_in[4];
    const float* W          = (const float*)d_in[5];
    const float* bias       = (const float*)d_in[6];

    float* out = (float*)d_out;
    const size_t nE = (size_t)ZB * NN * KNNv * DM;
    const size_t nK = (size_t)ZB * NN * KNNv;
    float* outE = out;
    float* outK = out + nE;
    float* outM = outK + nK;

    unsigned short* Wt    = (unsigned short*)d_ws;             // 64 KiB
    float*          bias2 = (float*)((char*)d_ws + 65536);     // 512 B
    float4*         Ca4   = (float4*)((char*)d_ws + 66048);    // 128 KiB

    caprep_kernel<<<32, 256, 0, stream>>>(C, Ca4);
    knn_kernel<<<ZB * NN / 8, 256, 0, stream>>>(Ca4, nm, outK, outM);
    wprep_kernel<<<32, 256, 0, stream>>>(W, gamma_, Wt);
    biasprep_kernel<<<1, 128, 0, stream>>>(W, beta_, bias, bias2);
    edge_kernel<<<(int)(nK / 64), 256, 0, stream>>>(C, outK, centers, Wt, bias2, outE);
}